// Round 9
// baseline (18790.318 us; speedup 1.0000x reference)
//
#include <hip/hip_runtime.h>
#include <hip/hip_bf16.h>

#define TSTEPS 4096
#define BATCH 16
#define HID 1024
#define DIN 147
#define KIN 160
#define KC  (HID + KIN)      /* 1184 = 37*32 : weight row = [w_hh(1024) | w_ih(160)] */
#define NWG 64               /* GRU workgroups: 1 col-block (16 cols) x 3 gate-waves each */
#define NFC 160              /* FC worker workgroups fused into the same launch */
#define NCLS 256
#define FCN 1024
#define KFC 576
#define FRONTIER 512         /* uint index into flags[]: byte 2048, own cache line */

typedef __attribute__((ext_vector_type(8))) short short8;
typedef __attribute__((ext_vector_type(4))) float floatx4;

__device__ __forceinline__ unsigned short f2b(float f) {
  __hip_bfloat16 h = __float2bfloat16(f);
  return *reinterpret_cast<unsigned short*>(&h);
}

#define GLOAD_LDS16(g, l) __builtin_amdgcn_global_load_lds( \
    (const __attribute__((address_space(1))) void*)(g), \
    (__attribute__((address_space(3))) void*)(l), 16, 0, 0)

// H layout (blocked): H[t][cb(64)][row(16)][col(16)] bf16.
//   tile(t) = 32KB; block cb = 512B contiguous = 4 FULL 128B lines, written by
//   exactly one producer WG with plain system-scope stores (R4-proven fastest).
// R9: LDS tile layout == global blocked layout (identity copy). Each 1KB DMA is
//   fully contiguous (8 whole lines, was 32x 32B gathers) and covers exactly
//   blocks {2p,2p+1}, so staging is gated per flag-pair (in-order frontier) —
//   fills overlap the straggler wait instead of bursting after the last flag.
//   MFMA A-frag (lane cn,quad; slice ks) = block 2ks+(quad>>1), row cn, half
//   quad&1 -> ds_read at base + ks*1024 (compile-time offsets, no swizzle).

// ---------------- pack: Xg (x-part bf16), aux bf16, H[0]=0, flags=0 ----------------
__global__ void k_pack(const float* __restrict__ x, const float* __restrict__ feat,
                       const float* __restrict__ aux1, const float* __restrict__ aux2,
                       const float* __restrict__ aux3,
                       unsigned short* __restrict__ Xg, unsigned short* __restrict__ H,
                       unsigned short* __restrict__ a2b, unsigned short* __restrict__ a3b,
                       unsigned int* __restrict__ flags) {
  const int t = blockIdx.x;
  const int tid = threadIdx.x;
  for (int i = tid; i < BATCH * KIN; i += 256) {
    int b = i / KIN, k = i - b * KIN;
    float v = 0.f;
    if (k < 80)       v = feat[((size_t)b * TSTEPS + t) * 80 + k];
    else if (k < 144) v = aux1[((size_t)b * TSTEPS + t) * 64 + (k - 80)];
    else if (k < 147) v = x[((size_t)b * TSTEPS + t) * 3 + (k - 144)];
    Xg[((size_t)t * BATCH + b) * KIN + k] = f2b(v);
  }
  for (int i = tid; i < BATCH * 64; i += 256) {
    int b = i >> 6, k = i & 63;
    a2b[(size_t)t * (BATCH * 64) + i] = f2b(aux2[((size_t)b * TSTEPS + t) * 64 + k]);
    a3b[(size_t)t * (BATCH * 64) + i] = f2b(aux3[((size_t)b * TSTEPS + t) * 64 + k]);
  }
  if (t == 0) {
    for (int i = tid; i < BATCH * HID; i += 256) H[i] = 0;  // h_{-1} = 0 (layout-agnostic)
    for (int i = tid; i < TSTEPS; i += 256) flags[i] = 0u;  // covers flags + FRONTIER
  }
}

// ---------------- weight convert: Wc=[w_hh|w_ih] bf16, w1..w4 bf16 ----------------
__global__ void k_wconv(const float* __restrict__ w_ih, const float* __restrict__ w_hh,
                        const float* __restrict__ w1, const float* __restrict__ w2,
                        const float* __restrict__ w3, const float* __restrict__ w4,
                        unsigned short* __restrict__ Wc,
                        unsigned short* __restrict__ w1b, unsigned short* __restrict__ w2b,
                        unsigned short* __restrict__ w3b, unsigned short* __restrict__ w4b) {
  const int bid = blockIdx.x, tid = threadIdx.x;
  if (bid < 3072) {
    const int row = bid;
    for (int k = tid; k < KC; k += 256) {
      float v = 0.f;
      if (k < HID) v = w_hh[(size_t)row * HID + k];
      else if (k < HID + DIN) v = w_ih[(size_t)row * DIN + (k - HID)];
      Wc[(size_t)row * KC + k] = f2b(v);
    }
  } else if (bid < 4096) {
    const int row = bid - 3072;
    for (int k = tid; k < KFC; k += 256) w1b[(size_t)row * KFC + k] = f2b(w1[(size_t)row * KFC + k]);
  } else if (bid < 4352) {
    const int row = bid - 4096;
    for (int k = tid; k < FCN; k += 256) w2b[(size_t)row * FCN + k] = f2b(w2[(size_t)row * FCN + k]);
  } else if (bid < 5376) {
    const int row = bid - 4352;
    for (int k = tid; k < KFC; k += 256) w3b[(size_t)row * KFC + k] = f2b(w3[(size_t)row * KFC + k]);
  } else {
    const int row = bid - 5376;
    for (int k = tid; k < FCN; k += 256) w4b[(size_t)row * FCN + k] = f2b(w4[(size_t)row * FCN + k]);
  }
}

// ---------------- fused persistent kernel ----------------
// Blocks 0..63   : GRU — R7 protocol (16B-stride flags, plain system-scope h
//                  stores -> vmcnt(0) -> flag store; WG0 relays frontier).
//                  R9: identity-copy staging with per-flag-pair in-order gating.
// Blocks 64..223 : FC workers, frontier-paced (R7, unchanged).
__launch_bounds__(192, 1)
__global__ void k_gru(const unsigned short* __restrict__ Wc,
                      const float* __restrict__ b_ih, const float* __restrict__ b_hh,
                      const unsigned short* __restrict__ Xg,
                      unsigned short* __restrict__ H,
                      unsigned int* __restrict__ flags,
                      const unsigned short* __restrict__ a2b, const unsigned short* __restrict__ a3b,
                      const unsigned short* __restrict__ w1b, const unsigned short* __restrict__ w2b,
                      const unsigned short* __restrict__ w3b, const unsigned short* __restrict__ w4b,
                      const float* __restrict__ b1, const float* __restrict__ b2,
                      const float* __restrict__ b3, const float* __restrict__ b4,
                      float* __restrict__ out) {
  __shared__ __align__(16) unsigned char smem[51712];   // union: GRU 36.3KB / FC 51.7KB

  const int tid  = threadIdx.x;
  const int wave = tid >> 6;
  const int lane = tid & 63;
  const int cn   = lane & 15;
  const int quad = lane >> 4;

  if (blockIdx.x < NWG) {
    // ================= GRU path =================
    const int wg   = blockIdx.x;        // 0..63 == col-block
    const int gate = wave;              // 0=r, 1=z, 2=n
    const int grow = gate * HID + wg * 16 + cn;

    unsigned short* lh = reinterpret_cast<unsigned short*>(smem);          // 32KB tile
    float* lds_z  = reinterpret_cast<float*>(smem + 32768);
    float* lds_hn = reinterpret_cast<float*>(smem + 32768 + 1024);
    float* lds_xn = reinterpret_cast<float*>(smem + 32768 + 2048);
    unsigned* lds_hout = reinterpret_cast<unsigned*>(smem + 32768 + 3072); // 512B bounce

    // resident B-fragments: 37 * 16B = 148 regs
    short8 wf[37];
    {
      const short8* wptr = reinterpret_cast<const short8*>(Wc + (size_t)grow * KC);
#pragma unroll
      for (int ks = 0; ks < 37; ks++) wf[ks] = wptr[ks * 4 + quad];
    }
    const float bih = b_ih[grow];
    const float bhh = b_hh[grow];
    const float brz = bih + bhh;

    float hprev[4] = {0.f, 0.f, 0.f, 0.f};  // gate-0 wave: fp32 carried state

    for (int t = 0; t < TSTEPS; t++) {
      // x-part (k in [1024,1184)): no h dependency -> before poll/barrier
      floatx4 accx = {0.f, 0.f, 0.f, 0.f};
      {
        const short8* xptr = reinterpret_cast<const short8*>(Xg + ((size_t)t * BATCH + cn) * KIN);
        short8 ax[5];
#pragma unroll
        for (int ks = 0; ks < 5; ks++) ax[ks] = xptr[ks * 4 + quad];
#pragma unroll
        for (int ks = 0; ks < 5; ks++)
          accx = __builtin_amdgcn_mfma_f32_16x16x32_bf16(ax[ks], wf[32 + ks], accx, 0, 0, 0);
      }

      // wave 1: gated incremental staging. DMA p (1KB, contiguous) covers blocks
      // {2p,2p+1}; issue it as soon as flags[2p],[2p+1] >= t. Own-WG flag must be
      // set before ANY issue (it proves our waves 0/2 finished reading lh(t-1):
      // own wave-0 sets flag only after its epilogue, which is after B2(t-1)).
      if (wave == 1) {
        const unsigned need = (unsigned)t;   // flag[cb] == t  means step t-1 done
        const char* Ht = reinterpret_cast<const char*>(H) + ((size_t)t << 15);
        char* lbase = reinterpret_cast<char*>(lh);
        const int loff = lane << 4;
        int next = 0;
        for (;;) {
          unsigned f = __hip_atomic_load(&flags[lane * 4], __ATOMIC_RELAXED,
                                         __HIP_MEMORY_SCOPE_SYSTEM);
          unsigned long long m = __ballot(f >= need);
          if ((m >> wg) & 1ull) {
            while (next < 32 && ((m >> (next * 2)) & 3ull) == 3ull) {
              GLOAD_LDS16(Ht + (next << 10) + loff, lbase + (next << 10));
              next++;
            }
            if (next == 32) break;
          }
        }
        // WG0 relays the proven frontier (all flags >= t observed)
        if (wg == 0 && lane == 0)
          __hip_atomic_store(&flags[FRONTIER], (unsigned)t, __ATOMIC_RELAXED,
                             __HIP_MEMORY_SCOPE_SYSTEM);
        asm volatile("s_waitcnt vmcnt(0)" ::: "memory");
      }
      asm volatile("" ::: "memory");
      __syncthreads();   // B1: tile staged; also h_{t-1} visible + LDS WAR protection

      floatx4 acc0 = {0.f, 0.f, 0.f, 0.f};
      floatx4 acc1 = {0.f, 0.f, 0.f, 0.f};
      {
        // blocked LDS: A-frag(ks) at (2ks + (quad>>1))*512 + cn*32 + (quad&1)*16
        const char* lhb = reinterpret_cast<const char*>(lh) +
                          (((quad >> 1) << 9) + (cn << 5) + ((quad & 1) << 4));
#pragma unroll
        for (int ks = 0; ks < 32; ks += 2) {
          short8 a0 = *reinterpret_cast<const short8*>(lhb + (ks << 10));
          short8 a1 = *reinterpret_cast<const short8*>(lhb + ((ks + 1) << 10));
          acc0 = __builtin_amdgcn_mfma_f32_16x16x32_bf16(a0, wf[ks],     acc0, 0, 0, 0);
          acc1 = __builtin_amdgcn_mfma_f32_16x16x32_bf16(a1, wf[ks + 1], acc1, 0, 0, 0);
        }
      }

      float rr[4];
      if (gate == 0) {
#pragma unroll
        for (int j = 0; j < 4; j++) {
          float g = acc0[j] + acc1[j] + accx[j] + brz;
          rr[j] = __builtin_amdgcn_rcpf(1.f + __expf(-g));
        }
      } else if (gate == 1) {
#pragma unroll
        for (int j = 0; j < 4; j++) {
          float g = acc0[j] + acc1[j] + accx[j] + brz;
          lds_z[(quad * 4 + j) * 16 + cn] = __builtin_amdgcn_rcpf(1.f + __expf(-g));
        }
      } else {
#pragma unroll
        for (int j = 0; j < 4; j++) {
          int idx = (quad * 4 + j) * 16 + cn;
          lds_hn[idx] = acc0[j] + acc1[j] + bhh;  // w_hh part + b_hh
          lds_xn[idx] = accx[j] + bih;            // w_ih part + b_ih
        }
      }
      __syncthreads();   // B2: gate values ready

      if (gate == 0) {
#pragma unroll
        for (int j = 0; j < 4; j++) {
          int idx = (quad * 4 + j) * 16 + cn;
          float z = lds_z[idx];
          float a = lds_xn[idx] + rr[j] * lds_hn[idx];
          float e2 = __expf(2.f * a);
          float n = 1.f - 2.f * __builtin_amdgcn_rcpf(e2 + 1.f);   // tanh(a)
          float h = (1.f - z) * n + z * hprev[j];
          hprev[j] = h;
          unsigned hv = (unsigned)f2b(h);
          unsigned pv = __shfl_xor(hv, 1);
          if ((cn & 1) == 0)
            lds_hout[(quad * 4 + j) * 8 + (cn >> 1)] = hv | (pv << 16);
        }
        // 8B contiguous per lane -> 4 FULL 128B lines, plain system-scope (R4)
        unsigned long long v8 = reinterpret_cast<unsigned long long*>(lds_hout)[lane];
        unsigned long long* dst =
            reinterpret_cast<unsigned long long*>(H + (size_t)(t + 1) * BATCH * HID + wg * 256) + lane;
        __hip_atomic_store(dst, v8, __ATOMIC_RELAXED, __HIP_MEMORY_SCOPE_SYSTEM);
        asm volatile("s_waitcnt vmcnt(0)" ::: "memory");  // data committed before flag
        if (lane == 0)
          __hip_atomic_store(&flags[wg * 4], (unsigned)(t + 1), __ATOMIC_RELAXED,
                             __HIP_MEMORY_SCOPE_SYSTEM);
      }
    }

    // close the frontier: prove all flags reached TSTEPS, then publish it
    if (wg == 0 && wave == 1) {
      for (;;) {
        unsigned f = __hip_atomic_load(&flags[lane * 4], __ATOMIC_RELAXED,
                                       __HIP_MEMORY_SCOPE_SYSTEM);
        if (__ballot(f >= (unsigned)TSTEPS) == ~0ull) break;
      }
      if (lane == 0)
        __hip_atomic_store(&flags[FRONTIER], (unsigned)TSTEPS, __ATOMIC_RELAXED,
                           __HIP_MEMORY_SCOPE_SYSTEM);
    }
  } else {
    // ================= FC worker path =================
    const int w = blockIdx.x - NWG;
    unsigned short (*lA)[584] = reinterpret_cast<unsigned short(*)[584]>(smem);
    float (*lZ)[260] = reinterpret_cast<float(*)[260]>(smem);
    unsigned short (*lO)[1032] = reinterpret_cast<unsigned short(*)[1032]>(smem + 18688);

    for (int idx = w; idx < TSTEPS * 2; idx += NFC) {
      const int t  = idx >> 1;
      const int br = idx & 1;
      const unsigned short* wAp = br ? w3b : w1b;
      const unsigned short* wBp = br ? w4b : w2b;
      const float* bA = br ? b3 : b1;
      const float* bB = br ? b4 : b2;
      const unsigned short* aux = br ? a3b : a2b;
      float* outp = out + (size_t)br * BATCH * TSTEPS * NCLS;

      // wait for h_t (tile t+1) via the frontier relay only (read-only line)
      if (tid == 0) {
        const unsigned need = (unsigned)(t + 1);
        for (;;) {
          unsigned f = __hip_atomic_load(&flags[FRONTIER], __ATOMIC_RELAXED,
                                         __HIP_MEMORY_SCOPE_SYSTEM);
          if (f >= need) break;
          __builtin_amdgcn_s_sleep(64);
        }
      }
      __syncthreads();

      // stage A1 = [h_t(512) | aux(64)], rows b=0..15 (blocked H tile t+1)
      {
        const unsigned short* hb = H + (size_t)(t + 1) * BATCH * HID;
        for (int cid = tid; cid < 16 * 72; cid += 192) {
          int r = cid / 72, off = (cid - r * 72) * 8;
          uint4 v;
          if (off < 512)
            v = *reinterpret_cast<const uint4*>(hb + ((size_t)(br * 32 + (off >> 4))) * 256 + r * 16 + (off & 15));
          else
            v = *reinterpret_cast<const uint4*>(aux + ((size_t)t * 16 + r) * 64 + (off - 512));
          *reinterpret_cast<uint4*>(&lA[r][off]) = v;
        }
      }
      __syncthreads();

      // GEMM1: (16 x 576) @ (576 x 1024), 64 col-tiles striped over 3 waves
      {
        short8 af[18];
#pragma unroll
        for (int ks = 0; ks < 18; ks++)
          af[ks] = *reinterpret_cast<const short8*>(&lA[cn][ks * 32 + quad * 8]);

        for (int nt = wave; nt < 64; nt += 3) {
          const int colg = nt * 16 + cn;
          const short8* bptr = reinterpret_cast<const short8*>(wAp + (size_t)colg * KFC);
          floatx4 acc = {0.f, 0.f, 0.f, 0.f};
#pragma unroll
          for (int ks = 0; ks < 18; ks++)
            acc = __builtin_amdgcn_mfma_f32_16x16x32_bf16(af[ks], bptr[ks * 4 + quad], acc, 0, 0, 0);
          const float bias = bA[colg];
#pragma unroll
          for (int j = 0; j < 4; j++) {
            float v = acc[j] + bias;
            v = v > 0.f ? v : 0.f;                 // relu
            lO[quad * 4 + j][colg] = f2b(v);
          }
        }
      }
      __syncthreads();

      // GEMM2: (16 x 1024) @ (1024 x 256), 16 col-tiles striped over 3 waves
      {
        short8 of[32];
#pragma unroll
        for (int ks = 0; ks < 32; ks++)
          of[ks] = *reinterpret_cast<const short8*>(&lO[cn][ks * 32 + quad * 8]);

        for (int nt = wave; nt < 16; nt += 3) {
          const int cls = nt * 16 + cn;
          const short8* bptr = reinterpret_cast<const short8*>(wBp + (size_t)cls * FCN);
          floatx4 acc = {0.f, 0.f, 0.f, 0.f};
#pragma unroll
          for (int ks = 0; ks < 32; ks++)
            acc = __builtin_amdgcn_mfma_f32_16x16x32_bf16(of[ks], bptr[ks * 4 + quad], acc, 0, 0, 0);
          const float bias = bB[cls];
#pragma unroll
          for (int j = 0; j < 4; j++)
            lZ[quad * 4 + j][cls] = acc[j] + bias;
        }
      }
      __syncthreads();

      // log_softmax per row: 128 threads = 16 rows x 8 threads, 32 vals each
      if (tid < 128) {
        const int r = tid >> 3, j = tid & 7;
        float vals[32];
        float m = -3.4e38f;
#pragma unroll
        for (int i = 0; i < 32; i++) {
          float v = lZ[r][j + 8 * i];
          vals[i] = v;
          m = fmaxf(m, v);
        }
#pragma unroll
        for (int s = 4; s > 0; s >>= 1) m = fmaxf(m, __shfl_xor(m, s, 8));
        float ssum = 0.f;
#pragma unroll
        for (int i = 0; i < 32; i++) ssum += __expf(vals[i] - m);
#pragma unroll
        for (int s = 4; s > 0; s >>= 1) ssum += __shfl_xor(ssum, s, 8);
        const float lse = m + __logf(ssum);
        float* orow = outp + ((size_t)r * TSTEPS + t) * NCLS;
#pragma unroll
        for (int i = 0; i < 32; i++) orow[j + 8 * i] = vals[i] - lse;
      }
      __syncthreads();   // protect lA/lZ reuse across loop iterations
    }
  }
}

extern "C" void kernel_launch(void* const* d_in, const int* in_sizes, int n_in,
                              void* d_out, int out_size, void* d_ws, size_t ws_size,
                              hipStream_t stream) {
  const float* x    = (const float*)d_in[0];
  const float* feat = (const float*)d_in[1];
  const float* aux1 = (const float*)d_in[2];
  const float* aux2 = (const float*)d_in[3];
  const float* aux3 = (const float*)d_in[4];
  const float* w_ih = (const float*)d_in[5];
  const float* w_hh = (const float*)d_in[6];
  const float* b_ih = (const float*)d_in[7];
  const float* b_hh = (const float*)d_in[8];
  const float* w1   = (const float*)d_in[9];
  const float* b1   = (const float*)d_in[10];
  const float* w2   = (const float*)d_in[11];
  const float* b2   = (const float*)d_in[12];
  const float* w3   = (const float*)d_in[13];
  const float* b3   = (const float*)d_in[14];
  const float* w4   = (const float*)d_in[15];
  const float* b4   = (const float*)d_in[16];
  float* out = (float*)d_out;

  char* p = (char*)d_ws;
  unsigned short* H   = (unsigned short*)p; p += (size_t)(TSTEPS + 1) * BATCH * HID * 2;
  unsigned short* Xg  = (unsigned short*)p; p += (size_t)TSTEPS * BATCH * KIN * 2;
  unsigned int*  flags = (unsigned int*)p;  p += (size_t)TSTEPS * 4;
  unsigned short* Wc  = (unsigned short*)p; p += (size_t)3072 * KC * 2;
  unsigned short* w1b = (unsigned short*)p; p += (size_t)1024 * KFC * 2;
  unsigned short* w2b = (unsigned short*)p; p += (size_t)256 * FCN * 2;
  unsigned short* w3b = (unsigned short*)p; p += (size_t)1024 * KFC * 2;
  unsigned short* w4b = (unsigned short*)p; p += (size_t)256 * FCN * 2;
  unsigned short* a2b = (unsigned short*)p; p += (size_t)TSTEPS * BATCH * 64 * 2;
  unsigned short* a3b = (unsigned short*)p; p += (size_t)TSTEPS * BATCH * 64 * 2;

  if ((size_t)(p - (char*)d_ws) > ws_size) return;  // ws too small: fail loudly via absmax

  k_pack<<<TSTEPS, 256, 0, stream>>>(x, feat, aux1, aux2, aux3, Xg, H, a2b, a3b, flags);
  k_wconv<<<5632, 256, 0, stream>>>(w_ih, w_hh, w1, w2, w3, w4, Wc, w1b, w2b, w3b, w4b);
  k_gru<<<NWG + NFC, 192, 0, stream>>>(Wc, b_ih, b_hh, Xg, H, flags,
                                       a2b, a3b, w1b, w2b, w3b, w4b,
                                       b1, b2, b3, b4, out);
}

// Round 10
// 13017.903 us; speedup vs baseline: 1.4434x; 1.4434x over previous
//
#include <hip/hip_runtime.h>
#include <hip/hip_bf16.h>

#define TSTEPS 4096
#define BATCH 16
#define HID 1024
#define DIN 147
#define KIN 160
#define KC  (HID + KIN)      /* 1184 = 37*32 : weight row = [w_hh(1024) | w_ih(160)] */
#define NWG 64               /* GRU workgroups: 1 col-block (16 cols) x 3 gate-waves each */
#define NFC 160              /* FC worker workgroups fused into the same launch */
#define NCLS 256
#define FCN 1024
#define KFC 576
#define FRONTIER 512         /* uint index into flags[]: byte 2048, own cache line */

typedef __attribute__((ext_vector_type(8))) short short8;
typedef __attribute__((ext_vector_type(4))) float floatx4;

__device__ __forceinline__ unsigned short f2b(float f) {
  __hip_bfloat16 h = __float2bfloat16(f);
  return *reinterpret_cast<unsigned short*>(&h);
}

#define GLOAD_LDS16(g, l) __builtin_amdgcn_global_load_lds( \
    (const __attribute__((address_space(1))) void*)(g), \
    (__attribute__((address_space(3))) void*)(l), 16, 0, 0)

// H layout (blocked): H[t][cb(64)][row(16)][col(16)] bf16.
//   tile(t) = 32KB; block cb = 512B contiguous = 4 FULL 128B lines, written by
//   exactly one producer WG with plain system-scope stores (R4-proven fastest).
// R10 = R8 staging control flow + R9 blocked LDS layout:
//   - poll ALL flags first, THEN issue 32 contiguous 1KB DMAs + one vmcnt(0).
//     (R9's interleaved poll/issue serialized on shared vmcnt: every poll after
//     the first DMA issue waits vmcnt(0) on outstanding fills — +46% regression.)
//   - LDS tile == global blocked layout (identity copy): conflict-free ds_reads
//     at compile-time offsets (R9 PROVED: SQ_LDS_BANK_CONFLICT 1.21e8 -> 2.1e7),
//     and each DMA is 8 whole cache lines (was 32x 32B gathers in R8).
//   MFMA A-frag (lane cn,quad; slice ks) = byte (2ks+(quad>>1))*512 + cn*32 +
//   (quad&1)*16 -> ds_read base + ks*1024.

// ---------------- pack: Xg (x-part bf16), aux bf16, H[0]=0, flags=0 ----------------
__global__ void k_pack(const float* __restrict__ x, const float* __restrict__ feat,
                       const float* __restrict__ aux1, const float* __restrict__ aux2,
                       const float* __restrict__ aux3,
                       unsigned short* __restrict__ Xg, unsigned short* __restrict__ H,
                       unsigned short* __restrict__ a2b, unsigned short* __restrict__ a3b,
                       unsigned int* __restrict__ flags) {
  const int t = blockIdx.x;
  const int tid = threadIdx.x;
  for (int i = tid; i < BATCH * KIN; i += 256) {
    int b = i / KIN, k = i - b * KIN;
    float v = 0.f;
    if (k < 80)       v = feat[((size_t)b * TSTEPS + t) * 80 + k];
    else if (k < 144) v = aux1[((size_t)b * TSTEPS + t) * 64 + (k - 80)];
    else if (k < 147) v = x[((size_t)b * TSTEPS + t) * 3 + (k - 144)];
    Xg[((size_t)t * BATCH + b) * KIN + k] = f2b(v);
  }
  for (int i = tid; i < BATCH * 64; i += 256) {
    int b = i >> 6, k = i & 63;
    a2b[(size_t)t * (BATCH * 64) + i] = f2b(aux2[((size_t)b * TSTEPS + t) * 64 + k]);
    a3b[(size_t)t * (BATCH * 64) + i] = f2b(aux3[((size_t)b * TSTEPS + t) * 64 + k]);
  }
  if (t == 0) {
    for (int i = tid; i < BATCH * HID; i += 256) H[i] = 0;  // h_{-1} = 0 (layout-agnostic)
    for (int i = tid; i < TSTEPS; i += 256) flags[i] = 0u;  // covers flags + FRONTIER
  }
}

// ---------------- weight convert: Wc=[w_hh|w_ih] bf16, w1..w4 bf16 ----------------
__global__ void k_wconv(const float* __restrict__ w_ih, const float* __restrict__ w_hh,
                        const float* __restrict__ w1, const float* __restrict__ w2,
                        const float* __restrict__ w3, const float* __restrict__ w4,
                        unsigned short* __restrict__ Wc,
                        unsigned short* __restrict__ w1b, unsigned short* __restrict__ w2b,
                        unsigned short* __restrict__ w3b, unsigned short* __restrict__ w4b) {
  const int bid = blockIdx.x, tid = threadIdx.x;
  if (bid < 3072) {
    const int row = bid;
    for (int k = tid; k < KC; k += 256) {
      float v = 0.f;
      if (k < HID) v = w_hh[(size_t)row * HID + k];
      else if (k < HID + DIN) v = w_ih[(size_t)row * DIN + (k - HID)];
      Wc[(size_t)row * KC + k] = f2b(v);
    }
  } else if (bid < 4096) {
    const int row = bid - 3072;
    for (int k = tid; k < KFC; k += 256) w1b[(size_t)row * KFC + k] = f2b(w1[(size_t)row * KFC + k]);
  } else if (bid < 4352) {
    const int row = bid - 4096;
    for (int k = tid; k < FCN; k += 256) w2b[(size_t)row * FCN + k] = f2b(w2[(size_t)row * FCN + k]);
  } else if (bid < 5376) {
    const int row = bid - 4352;
    for (int k = tid; k < KFC; k += 256) w3b[(size_t)row * KFC + k] = f2b(w3[(size_t)row * KFC + k]);
  } else {
    const int row = bid - 5376;
    for (int k = tid; k < FCN; k += 256) w4b[(size_t)row * FCN + k] = f2b(w4[(size_t)row * FCN + k]);
  }
}

// ---------------- fused persistent kernel ----------------
// Blocks 0..63   : GRU — R7/R8 protocol (16B-stride flags, plain system-scope h
//                  stores -> vmcnt(0) -> flag store; wave-1 polls ALL flags then
//                  bulk-stages; WG0 relays frontier). R10: blocked identity LDS.
// Blocks 64..223 : FC workers, frontier-paced (R7, unchanged).
__launch_bounds__(192, 1)
__global__ void k_gru(const unsigned short* __restrict__ Wc,
                      const float* __restrict__ b_ih, const float* __restrict__ b_hh,
                      const unsigned short* __restrict__ Xg,
                      unsigned short* __restrict__ H,
                      unsigned int* __restrict__ flags,
                      const unsigned short* __restrict__ a2b, const unsigned short* __restrict__ a3b,
                      const unsigned short* __restrict__ w1b, const unsigned short* __restrict__ w2b,
                      const unsigned short* __restrict__ w3b, const unsigned short* __restrict__ w4b,
                      const float* __restrict__ b1, const float* __restrict__ b2,
                      const float* __restrict__ b3, const float* __restrict__ b4,
                      float* __restrict__ out) {
  __shared__ __align__(16) unsigned char smem[51712];   // union: GRU 36.3KB / FC 51.7KB

  const int tid  = threadIdx.x;
  const int wave = tid >> 6;
  const int lane = tid & 63;
  const int cn   = lane & 15;
  const int quad = lane >> 4;

  if (blockIdx.x < NWG) {
    // ================= GRU path =================
    const int wg   = blockIdx.x;        // 0..63 == col-block
    const int gate = wave;              // 0=r, 1=z, 2=n
    const int grow = gate * HID + wg * 16 + cn;

    unsigned short* lh = reinterpret_cast<unsigned short*>(smem);          // 32KB tile
    float* lds_z  = reinterpret_cast<float*>(smem + 32768);
    float* lds_hn = reinterpret_cast<float*>(smem + 32768 + 1024);
    float* lds_xn = reinterpret_cast<float*>(smem + 32768 + 2048);
    unsigned* lds_hout = reinterpret_cast<unsigned*>(smem + 32768 + 3072); // 512B bounce

    // resident B-fragments: 37 * 16B = 148 regs
    short8 wf[37];
    {
      const short8* wptr = reinterpret_cast<const short8*>(Wc + (size_t)grow * KC);
#pragma unroll
      for (int ks = 0; ks < 37; ks++) wf[ks] = wptr[ks * 4 + quad];
    }
    const float bih = b_ih[grow];
    const float bhh = b_hh[grow];
    const float brz = bih + bhh;

    float hprev[4] = {0.f, 0.f, 0.f, 0.f};  // gate-0 wave: fp32 carried state

    for (int t = 0; t < TSTEPS; t++) {
      // x-part (k in [1024,1184)): no h dependency -> before poll/barrier
      floatx4 accx = {0.f, 0.f, 0.f, 0.f};
      {
        const short8* xptr = reinterpret_cast<const short8*>(Xg + ((size_t)t * BATCH + cn) * KIN);
        short8 ax[5];
#pragma unroll
        for (int ks = 0; ks < 5; ks++) ax[ks] = xptr[ks * 4 + quad];
#pragma unroll
        for (int ks = 0; ks < 5; ks++)
          accx = __builtin_amdgcn_mfma_f32_16x16x32_bf16(ax[ks], wf[32 + ks], accx, 0, 0, 0);
      }

      // wave 1: poll ALL 64 flags (16B stride), then issue 32 contiguous 1KB
      // DMAs back-to-back + single vmcnt(0). (Poll and DMA never interleave:
      // they share vmcnt, and a poll after DMA issue would drain the fills.)
      if (wave == 1) {
        const unsigned need = (unsigned)t;   // flag[wg] == t  means step t-1 done
        for (;;) {
          unsigned f = __hip_atomic_load(&flags[lane * 4], __ATOMIC_RELAXED,
                                         __HIP_MEMORY_SCOPE_SYSTEM);
          if (__ballot(f >= need) == ~0ull) break;
        }
        const char* Ht = reinterpret_cast<const char*>(H) + ((size_t)t << 15);
        char* lbase = reinterpret_cast<char*>(lh);
        const int loff = lane << 4;
#pragma unroll
        for (int i = 0; i < 32; i++)
          GLOAD_LDS16(Ht + (i << 10) + loff, lbase + (i << 10));
        // WG0 relays the proven frontier (issued after DMAs so staging never waits)
        if (wg == 0 && lane == 0)
          __hip_atomic_store(&flags[FRONTIER], (unsigned)t, __ATOMIC_RELAXED,
                             __HIP_MEMORY_SCOPE_SYSTEM);
        asm volatile("s_waitcnt vmcnt(0)" ::: "memory");
      }
      asm volatile("" ::: "memory");
      __syncthreads();   // B1: tile staged; also h_{t-1} visible + LDS WAR protection

      floatx4 acc0 = {0.f, 0.f, 0.f, 0.f};
      floatx4 acc1 = {0.f, 0.f, 0.f, 0.f};
      {
        // blocked LDS: A-frag(ks) at (2ks + (quad>>1))*512 + cn*32 + (quad&1)*16
        const char* lhb = reinterpret_cast<const char*>(lh) +
                          (((quad >> 1) << 9) + (cn << 5) + ((quad & 1) << 4));
#pragma unroll
        for (int ks = 0; ks < 32; ks += 2) {
          short8 a0 = *reinterpret_cast<const short8*>(lhb + (ks << 10));
          short8 a1 = *reinterpret_cast<const short8*>(lhb + ((ks + 1) << 10));
          acc0 = __builtin_amdgcn_mfma_f32_16x16x32_bf16(a0, wf[ks],     acc0, 0, 0, 0);
          acc1 = __builtin_amdgcn_mfma_f32_16x16x32_bf16(a1, wf[ks + 1], acc1, 0, 0, 0);
        }
      }

      float rr[4];
      if (gate == 0) {
#pragma unroll
        for (int j = 0; j < 4; j++) {
          float g = acc0[j] + acc1[j] + accx[j] + brz;
          rr[j] = __builtin_amdgcn_rcpf(1.f + __expf(-g));
        }
      } else if (gate == 1) {
#pragma unroll
        for (int j = 0; j < 4; j++) {
          float g = acc0[j] + acc1[j] + accx[j] + brz;
          lds_z[(quad * 4 + j) * 16 + cn] = __builtin_amdgcn_rcpf(1.f + __expf(-g));
        }
      } else {
#pragma unroll
        for (int j = 0; j < 4; j++) {
          int idx = (quad * 4 + j) * 16 + cn;
          lds_hn[idx] = acc0[j] + acc1[j] + bhh;  // w_hh part + b_hh
          lds_xn[idx] = accx[j] + bih;            // w_ih part + b_ih
        }
      }
      __syncthreads();   // B2: gate values ready

      if (gate == 0) {
#pragma unroll
        for (int j = 0; j < 4; j++) {
          int idx = (quad * 4 + j) * 16 + cn;
          float z = lds_z[idx];
          float a = lds_xn[idx] + rr[j] * lds_hn[idx];
          float e2 = __expf(2.f * a);
          float n = 1.f - 2.f * __builtin_amdgcn_rcpf(e2 + 1.f);   // tanh(a)
          float h = (1.f - z) * n + z * hprev[j];
          hprev[j] = h;
          unsigned hv = (unsigned)f2b(h);
          unsigned pv = __shfl_xor(hv, 1);
          if ((cn & 1) == 0)
            lds_hout[(quad * 4 + j) * 8 + (cn >> 1)] = hv | (pv << 16);
        }
        // 8B contiguous per lane -> 4 FULL 128B lines, plain system-scope (R4)
        unsigned long long v8 = reinterpret_cast<unsigned long long*>(lds_hout)[lane];
        unsigned long long* dst =
            reinterpret_cast<unsigned long long*>(H + (size_t)(t + 1) * BATCH * HID + wg * 256) + lane;
        __hip_atomic_store(dst, v8, __ATOMIC_RELAXED, __HIP_MEMORY_SCOPE_SYSTEM);
        asm volatile("s_waitcnt vmcnt(0)" ::: "memory");  // data committed before flag
        if (lane == 0)
          __hip_atomic_store(&flags[wg * 4], (unsigned)(t + 1), __ATOMIC_RELAXED,
                             __HIP_MEMORY_SCOPE_SYSTEM);
      }
    }

    // close the frontier: prove all flags reached TSTEPS, then publish it
    if (wg == 0 && wave == 1) {
      for (;;) {
        unsigned f = __hip_atomic_load(&flags[lane * 4], __ATOMIC_RELAXED,
                                       __HIP_MEMORY_SCOPE_SYSTEM);
        if (__ballot(f >= (unsigned)TSTEPS) == ~0ull) break;
      }
      if (lane == 0)
        __hip_atomic_store(&flags[FRONTIER], (unsigned)TSTEPS, __ATOMIC_RELAXED,
                           __HIP_MEMORY_SCOPE_SYSTEM);
    }
  } else {
    // ================= FC worker path =================
    const int w = blockIdx.x - NWG;
    unsigned short (*lA)[584] = reinterpret_cast<unsigned short(*)[584]>(smem);
    float (*lZ)[260] = reinterpret_cast<float(*)[260]>(smem);
    unsigned short (*lO)[1032] = reinterpret_cast<unsigned short(*)[1032]>(smem + 18688);

    for (int idx = w; idx < TSTEPS * 2; idx += NFC) {
      const int t  = idx >> 1;
      const int br = idx & 1;
      const unsigned short* wAp = br ? w3b : w1b;
      const unsigned short* wBp = br ? w4b : w2b;
      const float* bA = br ? b3 : b1;
      const float* bB = br ? b4 : b2;
      const unsigned short* aux = br ? a3b : a2b;
      float* outp = out + (size_t)br * BATCH * TSTEPS * NCLS;

      // wait for h_t (tile t+1) via the frontier relay only (read-only line)
      if (tid == 0) {
        const unsigned need = (unsigned)(t + 1);
        for (;;) {
          unsigned f = __hip_atomic_load(&flags[FRONTIER], __ATOMIC_RELAXED,
                                         __HIP_MEMORY_SCOPE_SYSTEM);
          if (f >= need) break;
          __builtin_amdgcn_s_sleep(64);
        }
      }
      __syncthreads();

      // stage A1 = [h_t(512) | aux(64)], rows b=0..15 (blocked H tile t+1)
      {
        const unsigned short* hb = H + (size_t)(t + 1) * BATCH * HID;
        for (int cid = tid; cid < 16 * 72; cid += 192) {
          int r = cid / 72, off = (cid - r * 72) * 8;
          uint4 v;
          if (off < 512)
            v = *reinterpret_cast<const uint4*>(hb + ((size_t)(br * 32 + (off >> 4))) * 256 + r * 16 + (off & 15));
          else
            v = *reinterpret_cast<const uint4*>(aux + ((size_t)t * 16 + r) * 64 + (off - 512));
          *reinterpret_cast<uint4*>(&lA[r][off]) = v;
        }
      }
      __syncthreads();

      // GEMM1: (16 x 576) @ (576 x 1024), 64 col-tiles striped over 3 waves
      {
        short8 af[18];
#pragma unroll
        for (int ks = 0; ks < 18; ks++)
          af[ks] = *reinterpret_cast<const short8*>(&lA[cn][ks * 32 + quad * 8]);

        for (int nt = wave; nt < 64; nt += 3) {
          const int colg = nt * 16 + cn;
          const short8* bptr = reinterpret_cast<const short8*>(wAp + (size_t)colg * KFC);
          floatx4 acc = {0.f, 0.f, 0.f, 0.f};
#pragma unroll
          for (int ks = 0; ks < 18; ks++)
            acc = __builtin_amdgcn_mfma_f32_16x16x32_bf16(af[ks], bptr[ks * 4 + quad], acc, 0, 0, 0);
          const float bias = bA[colg];
#pragma unroll
          for (int j = 0; j < 4; j++) {
            float v = acc[j] + bias;
            v = v > 0.f ? v : 0.f;                 // relu
            lO[quad * 4 + j][colg] = f2b(v);
          }
        }
      }
      __syncthreads();

      // GEMM2: (16 x 1024) @ (1024 x 256), 16 col-tiles striped over 3 waves
      {
        short8 of[32];
#pragma unroll
        for (int ks = 0; ks < 32; ks++)
          of[ks] = *reinterpret_cast<const short8*>(&lO[cn][ks * 32 + quad * 8]);

        for (int nt = wave; nt < 16; nt += 3) {
          const int cls = nt * 16 + cn;
          const short8* bptr = reinterpret_cast<const short8*>(wBp + (size_t)cls * FCN);
          floatx4 acc = {0.f, 0.f, 0.f, 0.f};
#pragma unroll
          for (int ks = 0; ks < 32; ks++)
            acc = __builtin_amdgcn_mfma_f32_16x16x32_bf16(of[ks], bptr[ks * 4 + quad], acc, 0, 0, 0);
          const float bias = bB[cls];
#pragma unroll
          for (int j = 0; j < 4; j++)
            lZ[quad * 4 + j][cls] = acc[j] + bias;
        }
      }
      __syncthreads();

      // log_softmax per row: 128 threads = 16 rows x 8 threads, 32 vals each
      if (tid < 128) {
        const int r = tid >> 3, j = tid & 7;
        float vals[32];
        float m = -3.4e38f;
#pragma unroll
        for (int i = 0; i < 32; i++) {
          float v = lZ[r][j + 8 * i];
          vals[i] = v;
          m = fmaxf(m, v);
        }
#pragma unroll
        for (int s = 4; s > 0; s >>= 1) m = fmaxf(m, __shfl_xor(m, s, 8));
        float ssum = 0.f;
#pragma unroll
        for (int i = 0; i < 32; i++) ssum += __expf(vals[i] - m);
#pragma unroll
        for (int s = 4; s > 0; s >>= 1) ssum += __shfl_xor(ssum, s, 8);
        const float lse = m + __logf(ssum);
        float* orow = outp + ((size_t)r * TSTEPS + t) * NCLS;
#pragma unroll
        for (int i = 0; i < 32; i++) orow[j + 8 * i] = vals[i] - lse;
      }
      __syncthreads();   // protect lA/lZ reuse across loop iterations
    }
  }
}

extern "C" void kernel_launch(void* const* d_in, const int* in_sizes, int n_in,
                              void* d_out, int out_size, void* d_ws, size_t ws_size,
                              hipStream_t stream) {
  const float* x    = (const float*)d_in[0];
  const float* feat = (const float*)d_in[1];
  const float* aux1 = (const float*)d_in[2];
  const float* aux2 = (const float*)d_in[3];
  const float* aux3 = (const float*)d_in[4];
  const float* w_ih = (const float*)d_in[5];
  const float* w_hh = (const float*)d_in[6];
  const float* b_ih = (const float*)d_in[7];
  const float* b_hh = (const float*)d_in[8];
  const float* w1   = (const float*)d_in[9];
  const float* b1   = (const float*)d_in[10];
  const float* w2   = (const float*)d_in[11];
  const float* b2   = (const float*)d_in[12];
  const float* w3   = (const float*)d_in[13];
  const float* b3   = (const float*)d_in[14];
  const float* w4   = (const float*)d_in[15];
  const float* b4   = (const float*)d_in[16];
  float* out = (float*)d_out;

  char* p = (char*)d_ws;
  unsigned short* H   = (unsigned short*)p; p += (size_t)(TSTEPS + 1) * BATCH * HID * 2;
  unsigned short* Xg  = (unsigned short*)p; p += (size_t)TSTEPS * BATCH * KIN * 2;
  unsigned int*  flags = (unsigned int*)p;  p += (size_t)TSTEPS * 4;
  unsigned short* Wc  = (unsigned short*)p; p += (size_t)3072 * KC * 2;
  unsigned short* w1b = (unsigned short*)p; p += (size_t)1024 * KFC * 2;
  unsigned short* w2b = (unsigned short*)p; p += (size_t)256 * FCN * 2;
  unsigned short* w3b = (unsigned short*)p; p += (size_t)1024 * KFC * 2;
  unsigned short* w4b = (unsigned short*)p; p += (size_t)256 * FCN * 2;
  unsigned short* a2b = (unsigned short*)p; p += (size_t)TSTEPS * BATCH * 64 * 2;
  unsigned short* a3b = (unsigned short*)p; p += (size_t)TSTEPS * BATCH * 64 * 2;

  if ((size_t)(p - (char*)d_ws) > ws_size) return;  // ws too small: fail loudly via absmax

  k_pack<<<TSTEPS, 256, 0, stream>>>(x, feat, aux1, aux2, aux3, Xg, H, a2b, a3b, flags);
  k_wconv<<<5632, 256, 0, stream>>>(w_ih, w_hh, w1, w2, w3, w4, Wc, w1b, w2b, w3b, w4b);
  k_gru<<<NWG + NFC, 192, 0, stream>>>(Wc, b_ih, b_hh, Xg, H, flags,
                                       a2b, a3b, w1b, w2b, w3b, w4b,
                                       b1, b2, b3, b4, out);
}